// Round 1
// baseline (157.868 us; speedup 1.0000x reference)
//
#include <hip/hip_runtime.h>
#include <math.h>

// Problem constants (match reference)
constexpr int V = 131072;   // vocab / leaves
constexpr int D = 17;       // tree depth
constexpr int B = 16384;    // batch
constexpr int E = 128;      // embedding dim
constexpr int WAVES_PER_BLOCK = 4;          // 256 threads
constexpr int NBLK = B / WAVES_PER_BLOCK;   // 4096 blocks -> 4096 partials

// One wave per sample. Lane i holds embedding float2 (covers all 128 floats).
// All 17 W-row loads are independent (path indices are arithmetic from
// word_idx), so they issue as one batch of global_load_dwordx2 and the
// latency is hidden by occupancy.
__global__ __launch_bounds__(256) void hsm_partial(
    const float* __restrict__ emb,
    const int*   __restrict__ widx,
    const float* __restrict__ W,
    const float* __restrict__ bias,
    float*       __restrict__ partial)
{
    const int lane   = threadIdx.x & 63;
    const int wid    = threadIdx.x >> 6;
    const int sample = blockIdx.x * WAVES_PER_BLOCK + wid;

    // embedding: 64 lanes x float2 = 128 floats, read once, kept in regs
    const float2 e = ((const float2*)(emb + (size_t)sample * E))[lane];

    // walk leaf -> root, record parent indices + direction bits
    int node = widx[sample] + (V - 1);
    int par[D];
    unsigned dirbits = 0;
    #pragma unroll
    for (int d = 0; d < D; ++d) {
        dirbits |= (unsigned)(node & 1) << d;   // 1 iff came from left child
        node = (node - 1) >> 1;
        par[d] = node;
    }

    // issue all 17 row gathers + 17 bias broadcasts up front (independent)
    float2 w[D];
    float  bn[D];
    #pragma unroll
    for (int d = 0; d < D; ++d) {
        w[d]  = ((const float2*)(W + (size_t)par[d] * E))[lane];
        bn[d] = bias[par[d]];    // all lanes same addr -> broadcast
    }

    // per-node logit via wave butterfly reduce, then stable BCE-with-logits
    float loss = 0.0f;
    #pragma unroll
    for (int d = 0; d < D; ++d) {
        float p = fmaf(e.x, w[d].x, e.y * w[d].y);
        #pragma unroll
        for (int off = 32; off >= 1; off >>= 1)
            p += __shfl_xor(p, off, 64);
        const float s = p + bn[d];
        const float t = (float)((dirbits >> d) & 1u);
        loss += fmaxf(s, 0.0f) - s * t + log1pf(expf(-fabsf(s)));
    }

    // block reduce (4 waves) -> one partial per block (deterministic, no atomics)
    __shared__ float red[WAVES_PER_BLOCK];
    if (lane == 0) red[wid] = loss;
    __syncthreads();
    if (threadIdx.x == 0) {
        float tot = red[0];
        #pragma unroll
        for (int i = 1; i < WAVES_PER_BLOCK; ++i) tot += red[i];
        partial[blockIdx.x] = tot;
    }
}

__global__ __launch_bounds__(256) void hsm_reduce(
    const float* __restrict__ partial,
    float*       __restrict__ out)
{
    float s = 0.0f;
    for (int i = threadIdx.x; i < NBLK; i += 256) s += partial[i];
    #pragma unroll
    for (int off = 32; off >= 1; off >>= 1)
        s += __shfl_xor(s, off, 64);

    __shared__ float red[4];
    const int lane = threadIdx.x & 63, wid = threadIdx.x >> 6;
    if (lane == 0) red[wid] = s;
    __syncthreads();
    if (threadIdx.x == 0)
        out[0] = (red[0] + red[1] + red[2] + red[3]) * (1.0f / (float)B);
}

extern "C" void kernel_launch(void* const* d_in, const int* in_sizes, int n_in,
                              void* d_out, int out_size, void* d_ws, size_t ws_size,
                              hipStream_t stream) {
    const float* emb  = (const float*)d_in[0];   // [B,E] f32
    const int*   widx = (const int*)  d_in[1];   // [B]   i32
    const float* W    = (const float*)d_in[2];   // [V-1,E] f32
    const float* bias = (const float*)d_in[3];   // [V-1] f32
    float* out     = (float*)d_out;
    float* partial = (float*)d_ws;               // NBLK floats, fully overwritten

    hsm_partial<<<NBLK, 256, 0, stream>>>(emb, widx, W, bias, partial);
    hsm_reduce<<<1, 256, 0, stream>>>(partial, out);
}

// Round 2
// 128.398 us; speedup vs baseline: 1.2295x; 1.2295x over previous
//
#include <hip/hip_runtime.h>
#include <math.h>

// Problem constants (match reference)
constexpr int V = 131072;   // vocab / leaves
constexpr int D = 17;       // tree depth
constexpr int B = 16384;    // batch
constexpr int E = 128;      // embedding dim

constexpr int PAIRS = B * D;            // 278528 (sample, node) pairs
constexpr int BLK   = 256;
constexpr int NBLK  = PAIRS / BLK;      // 1088 exactly

// One thread per (sample, tree-level) pair. Each thread:
//   - computes its path node index arithmetically (heap layout, no chase)
//   - serial 128-elem dot product (32 x float4, 4 accumulators for ILP)
//   - one stable BCE-with-logits
//   - 6-shuffle wave reduce + LDS block reduce -> 1 partial per block
// This gives ~170 useful VALU ops per ~50 overhead ops (vs 34:300 before).
__global__ __launch_bounds__(256) void hsm_pairs(
    const float* __restrict__ emb,
    const int*   __restrict__ widx,
    const float* __restrict__ W,
    const float* __restrict__ bias,
    float*       __restrict__ partial)
{
    const int tid = blockIdx.x * BLK + threadIdx.x;
    const int b   = tid / D;            // compiler -> magic mul
    const int d   = tid - b * D;

    // heap path arithmetic: leaf 1-indexed j0 = widx + V; child at step d is
    // j0>>d; its parent is the node we score; dir=1 iff child was a left child.
    const int   j0   = widx[b] + V;
    const int   jc   = j0 >> d;
    const int   node = (jc >> 1) - 1;
    const float t    = (float)(1 - (jc & 1));

    const float4* er = (const float4*)(emb + (size_t)b    * E);
    const float4* wr = (const float4*)(W   + (size_t)node * E);

    float a0 = 0.f, a1 = 0.f, a2 = 0.f, a3 = 0.f;
    #pragma unroll
    for (int i = 0; i < E / 16; ++i) {      // 8 iters x 64B per operand
        float4 e0 = er[i*4+0], e1 = er[i*4+1], e2 = er[i*4+2], e3 = er[i*4+3];
        float4 w0 = wr[i*4+0], w1 = wr[i*4+1], w2 = wr[i*4+2], w3 = wr[i*4+3];
        a0 = fmaf(e0.x, w0.x, fmaf(e0.y, w0.y, fmaf(e0.z, w0.z, fmaf(e0.w, w0.w, a0))));
        a1 = fmaf(e1.x, w1.x, fmaf(e1.y, w1.y, fmaf(e1.z, w1.z, fmaf(e1.w, w1.w, a1))));
        a2 = fmaf(e2.x, w2.x, fmaf(e2.y, w2.y, fmaf(e2.z, w2.z, fmaf(e2.w, w2.w, a2))));
        a3 = fmaf(e3.x, w3.x, fmaf(e3.y, w3.y, fmaf(e3.z, w3.z, fmaf(e3.w, w3.w, a3))));
    }
    const float s = (a0 + a1) + (a2 + a3) + bias[node];

    // stable BCE-with-logits
    float loss = fmaxf(s, 0.0f) - s * t + log1pf(expf(-fabsf(s)));

    // wave reduce (6 shuffles) + block reduce
    #pragma unroll
    for (int off = 32; off >= 1; off >>= 1)
        loss += __shfl_xor(loss, off, 64);

    __shared__ float red[BLK / 64];
    const int lane = threadIdx.x & 63, wid = threadIdx.x >> 6;
    if (lane == 0) red[wid] = loss;
    __syncthreads();
    if (threadIdx.x == 0)
        partial[blockIdx.x] = (red[0] + red[1]) + (red[2] + red[3]);
}

__global__ __launch_bounds__(256) void hsm_reduce(
    const float* __restrict__ partial,
    float*       __restrict__ out)
{
    float s = 0.0f;
    for (int i = threadIdx.x; i < NBLK; i += 256) s += partial[i];
    #pragma unroll
    for (int off = 32; off >= 1; off >>= 1)
        s += __shfl_xor(s, off, 64);

    __shared__ float red[4];
    const int lane = threadIdx.x & 63, wid = threadIdx.x >> 6;
    if (lane == 0) red[wid] = s;
    __syncthreads();
    if (threadIdx.x == 0)
        out[0] = ((red[0] + red[1]) + (red[2] + red[3])) * (1.0f / (float)B);
}

extern "C" void kernel_launch(void* const* d_in, const int* in_sizes, int n_in,
                              void* d_out, int out_size, void* d_ws, size_t ws_size,
                              hipStream_t stream) {
    const float* emb  = (const float*)d_in[0];   // [B,E] f32
    const int*   widx = (const int*)  d_in[1];   // [B]   i32
    const float* W    = (const float*)d_in[2];   // [V-1,E] f32
    const float* bias = (const float*)d_in[3];   // [V-1] f32
    float* out     = (float*)d_out;
    float* partial = (float*)d_ws;               // NBLK floats, fully overwritten

    hsm_pairs<<<NBLK, BLK, 0, stream>>>(emb, widx, W, bias, partial);
    hsm_reduce<<<1, 256, 0, stream>>>(partial, out);
}

// Round 3
// 107.849 us; speedup vs baseline: 1.4638x; 1.1905x over previous
//
#include <hip/hip_runtime.h>
#include <math.h>

// Problem constants (match reference)
constexpr int V = 131072;   // vocab / leaves
constexpr int D = 17;       // tree depth
constexpr int B = 16384;    // batch
constexpr int E = 128;      // embedding dim

constexpr int LPG  = 16;                  // lanes per (sample) group
constexpr int SPB  = 16;                  // samples per block (256 threads / 16)
constexpr int NBLK = B / SPB;             // 1024 blocks

// 16 lanes cooperate on one sample; a wave holds 4 samples; loop over the 17
// tree levels with the embedding row register-cached. W row reads are two
// 256B fully-coalesced group loads (vs 64-way gather in the previous round).
// BCE uses __expf/__logf (absolute per-term error <1e-5; threshold is 0.275
// on the batch mean).
__global__ __launch_bounds__(256) void hsm_main(
    const float* __restrict__ emb,
    const int*   __restrict__ widx,
    const float* __restrict__ W,
    const float* __restrict__ bias,
    float*       __restrict__ partial)
{
    const int lane = threadIdx.x & 63;
    const int wid  = threadIdx.x >> 6;
    const int g    = lane >> 4;            // subgroup 0..3 within wave
    const int l    = lane & 15;            // lane within subgroup
    const int b    = blockIdx.x * SPB + wid * 4 + g;

    // embedding row: 16 lanes x 2 float4 = 512 B, register-cached for all 17 levels
    const float4* er = (const float4*)(emb + (size_t)b * E);
    const float4 e0 = er[l];
    const float4 e1 = er[l + LPG];

    const int j0 = widx[b] + V;            // 1-indexed leaf in heap layout

    float loss = 0.0f;
    #pragma unroll
    for (int d = 0; d < D; ++d) {
        const int   jc   = j0 >> d;        // 1-indexed child at this step
        const int   node = (jc >> 1) - 1;  // 0-indexed parent (scored node)
        const float t    = (float)(1 - (jc & 1));

        const float4* wr = (const float4*)(W + (size_t)node * E);
        const float4 w0 = wr[l];
        const float4 w1 = wr[l + LPG];

        float p;
        p = fmaf(e0.x, w0.x, e0.y * w0.y);
        p = fmaf(e0.z, w0.z, p);
        p = fmaf(e0.w, w0.w, p);
        p = fmaf(e1.x, w1.x, p);
        p = fmaf(e1.y, w1.y, p);
        p = fmaf(e1.z, w1.z, p);
        p = fmaf(e1.w, w1.w, p);

        // reduce across the 16 lanes of the subgroup
        p += __shfl_xor(p, 1, 64);
        p += __shfl_xor(p, 2, 64);
        p += __shfl_xor(p, 4, 64);
        p += __shfl_xor(p, 8, 64);

        const float s = p + bias[node];
        loss += fmaxf(s, 0.0f) - s * t + __logf(1.0f + __expf(-fabsf(s)));
    }

    // combine the 4 subgroups of the wave (each lane holds its group's sum)
    loss += __shfl_xor(loss, 16, 64);
    loss += __shfl_xor(loss, 32, 64);

    __shared__ float red[4];
    if (lane == 0) red[wid] = loss;
    __syncthreads();
    if (threadIdx.x == 0)
        partial[blockIdx.x] = (red[0] + red[1]) + (red[2] + red[3]);
}

__global__ __launch_bounds__(256) void hsm_reduce(
    const float* __restrict__ partial,
    float*       __restrict__ out)
{
    float s = 0.0f;
    for (int i = threadIdx.x; i < NBLK; i += 256) s += partial[i];
    #pragma unroll
    for (int off = 32; off >= 1; off >>= 1)
        s += __shfl_xor(s, off, 64);

    __shared__ float red[4];
    const int lane = threadIdx.x & 63, wid = threadIdx.x >> 6;
    if (lane == 0) red[wid] = s;
    __syncthreads();
    if (threadIdx.x == 0)
        out[0] = ((red[0] + red[1]) + (red[2] + red[3])) * (1.0f / (float)B);
}

extern "C" void kernel_launch(void* const* d_in, const int* in_sizes, int n_in,
                              void* d_out, int out_size, void* d_ws, size_t ws_size,
                              hipStream_t stream) {
    const float* emb  = (const float*)d_in[0];   // [B,E] f32
    const int*   widx = (const int*)  d_in[1];   // [B]   i32
    const float* W    = (const float*)d_in[2];   // [V-1,E] f32
    const float* bias = (const float*)d_in[3];   // [V-1] f32
    float* out     = (float*)d_out;
    float* partial = (float*)d_ws;               // NBLK floats, fully overwritten

    hsm_main<<<NBLK, 256, 0, stream>>>(emb, widx, W, bias, partial);
    hsm_reduce<<<1, 256, 0, stream>>>(partial, out);
}